// Round 10
// baseline (23.916 us; speedup 1.0000x reference)
//
#include <hip/hip_runtime.h>

#define VOCAB 1024
#define ARCS  16
#define CHAIN 3
#define START_STATE 0
#define WAVE 64
#define WAVES_PER_BLOCK 4
#define BLOCK (WAVE * WAVES_PER_BLOCK)
#define NCHUNK (VOCAB / (WAVE * 4))
#define SLOTS (CHAIN * ARCS)          // 48 overlay slots per hypothesis

typedef float f32x4 __attribute__((ext_vector_type(4)));
typedef int   i32x4 __attribute__((ext_vector_type(4)));

// ============================ Kernel A: gather ==============================
// 1 hyp/wave, zero LDS. Pays ALL scattered-read latency; writes only a
// compact pre-deduped overlay (48 x {lab,score,next} + accf) to scratch.
__global__ __launch_bounds__(BLOCK, 8) void build_overlay_kernel(
    const float* __restrict__ arcs_weights,
    const float* __restrict__ backoff_weights,
    const int*   __restrict__ ilabels,
    const int*   __restrict__ to_states,
    const int*   __restrict__ backoff_to,
    const int*   __restrict__ state_start,
    const int*   __restrict__ state_end,
    const int*   __restrict__ states,
    int*         __restrict__ ws_lab,
    float*       __restrict__ ws_sc,
    float*       __restrict__ ws_ns,
    float*       __restrict__ ws_accf,
    int B)
{
    const int lane = threadIdx.x & (WAVE - 1);
    const int wid  = __builtin_amdgcn_readfirstlane(threadIdx.x >> 6);
    const int b    = blockIdx.x * WAVES_PER_BLOCK + wid;
    if (b >= B) return;

    // Chain walk, branchless (backoff_weights[0]==0, backoff_to[0]==0:
    // START self-loops at zero cost). Wave-uniform -> scalarized.
    int cur = states[b];
    float acc = 0.0f;
    const int   cs0 = cur;  const float ca0 = acc;
    acc += backoff_weights[cur];  cur = backoff_to[cur];
    const int   cs1 = cur;  const float ca1 = acc;
    acc += backoff_weights[cur];  cur = backoff_to[cur];
    const int   cs2 = cur;  const float ca2 = acc;
    acc += backoff_weights[cur];
    const float accf = acc;

    // Arc fetch: lanes 0..47, level = lane>>4, arc = lane&15.
    const int level = lane >> 4;
    const int arc   = lane & (ARCS - 1);
    int   lab = -1;
    float sc  = 0.0f, fns = 0.0f;
    bool  ok  = false;
    if (lane < SLOTS) {
        const int   s    = (level == 0) ? cs0 : (level == 1) ? cs1 : cs2;
        const float cacc = (level == 0) ? ca0 : (level == 1) ? ca1 : ca2;
        if (s != START_STATE) {
            const int idx = state_start[s] + arc;
            if (idx < state_end[s]) {
                lab = ilabels[idx];
                sc  = cacc + arcs_weights[idx];
                fns = (float)to_states[idx];
                ok  = true;
            }
        }
    }

    // In-register dedup: kill a lane if a LOWER level (higher n-gram order,
    // higher priority) holds the same label. Invalid lanes carry lab = -1,
    // which never matches a valid lane's label. (Proven R5/R6, absmax 0.)
    int kill = 0;
    #pragma unroll
    for (int k = 0; k < 2 * ARCS; ++k) {
        const int lk = __builtin_amdgcn_readlane(lab, k);
        if (k < ARCS) kill |= (int)(level >= 1) & (int)(lab == lk);
        else          kill |= (int)(level == 2) & (int)(lab == lk);
    }

    // Compact coalesced writes: 3 x 192B per hyp (+1 scalar).
    if (lane < SLOTS) {
        const int slot = b * SLOTS + lane;
        ws_lab[slot] = (ok && !kill) ? lab : -1;
        ws_sc [slot] = sc;
        ws_ns [slot] = fns;
    }
    if (lane == 0) ws_accf[b] = accf;
}

// ============================ Kernel B: stream ==============================
// 1 hyp/wave. Preamble = 3 coalesced 192B loads + 1 scalar load; no
// dependent scattered chains. who-table (1KB/wave) + bpermute merge (R8),
// single commit round (entries pre-deduped -> distinct labels).
__global__ __launch_bounds__(BLOCK, 8) void stream_merge_kernel(
    const float* __restrict__ arcs_weights,
    const int*   __restrict__ to_states,
    const int*   __restrict__ ws_lab,
    const float* __restrict__ ws_sc,
    const float* __restrict__ ws_ns,
    const float* __restrict__ ws_accf,
    float*       __restrict__ out_scores,
    float*       __restrict__ out_next,
    int B)
{
    __shared__ unsigned char s_who[WAVES_PER_BLOCK][VOCAB];  // 4 KB total

    const int lane = threadIdx.x & (WAVE - 1);
    const int wid  = __builtin_amdgcn_readfirstlane(threadIdx.x >> 6);
    const int b    = blockIdx.x * WAVES_PER_BLOCK + wid;
    if (b >= B) return;

    unsigned char* __restrict__ who = s_who[wid];

    // Coalesced overlay fetch (lanes 0..47) + uniform accf (s_load).
    int lab = -1, sci = 0, nsi = 0;
    if (lane < SLOTS) {
        const int slot = b * SLOTS + lane;
        lab = ws_lab[slot];
        sci = __float_as_int(ws_sc[slot]);
        nsi = __float_as_int(ws_ns[slot]);
    }
    const float accf = ws_accf[b];

    // Sentinel-init own 1KB who-table, then single commit round.
    *(i32x4*)&who[lane * 16] = (i32x4){-1, -1, -1, -1};
    __builtin_amdgcn_sched_barrier(0);
    if (lab >= 0) who[lab] = (unsigned char)lane;
    __builtin_amdgcn_sched_barrier(0);

    // Merge + single coalesced store pass (proven R8 structure).
    float* __restrict__ so = out_scores + (size_t)b * VOCAB;
    float* __restrict__ no = out_next   + (size_t)b * VOCAB;
    #pragma unroll
    for (int i = 0; i < NCHUNK; ++i) {
        const int v = (lane + i * WAVE) * 4;
        const unsigned w4 = *(const unsigned*)&who[v];
        const f32x4 dwv = *(const f32x4*)&arcs_weights[v];  // L1-hot
        const i32x4 dnv = *(const i32x4*)&to_states[v];     // L1-hot
        f32x4 rs, rx;
        #pragma unroll
        for (int j = 0; j < 4; ++j) {
            const unsigned wb = (w4 >> (8 * j)) & 0xFFu;
            const float scv = __int_as_float(
                __builtin_amdgcn_ds_bpermute((int)(wb << 2), sci));
            const float nsv = __int_as_float(
                __builtin_amdgcn_ds_bpermute((int)(wb << 2), nsi));
            const bool hit = (wb != 0xFFu);
            rs[j] = hit ? scv : accf + dwv[j];
            rx[j] = hit ? nsv : (float)dnv[j];
        }
        *(f32x4*)&so[v] = rs;
        *(f32x4*)&no[v] = rx;
    }
}

// ==================== Fallback: proven R8 single kernel =====================
__global__ __launch_bounds__(BLOCK, 8) void ngram_fused_kernel(
    const float* __restrict__ arcs_weights,
    const float* __restrict__ backoff_weights,
    const int*   __restrict__ ilabels,
    const int*   __restrict__ to_states,
    const int*   __restrict__ backoff_to,
    const int*   __restrict__ state_start,
    const int*   __restrict__ state_end,
    const int*   __restrict__ states,
    float*       __restrict__ out_scores,
    float*       __restrict__ out_next,
    int B)
{
    __shared__ unsigned char s_who[WAVES_PER_BLOCK][VOCAB];

    const int lane = threadIdx.x & (WAVE - 1);
    const int wid  = __builtin_amdgcn_readfirstlane(threadIdx.x >> 6);
    const int b    = blockIdx.x * WAVES_PER_BLOCK + wid;
    if (b >= B) return;

    unsigned char* __restrict__ who = s_who[wid];
    int cur = states[b];
    *(i32x4*)&who[lane * 16] = (i32x4){-1, -1, -1, -1};

    float acc = 0.0f;
    const int   cs0 = cur;  const float ca0 = acc;
    acc += backoff_weights[cur];  cur = backoff_to[cur];
    const int   cs1 = cur;  const float ca1 = acc;
    acc += backoff_weights[cur];  cur = backoff_to[cur];
    const int   cs2 = cur;  const float ca2 = acc;
    acc += backoff_weights[cur];
    const float accf = acc;

    const int level = lane >> 4;
    const int arc   = lane & (ARCS - 1);
    int   lab = -1;
    float sc  = 0.0f, fns = 0.0f;
    bool  ok  = false;
    if (lane < SLOTS) {
        const int   s    = (level == 0) ? cs0 : (level == 1) ? cs1 : cs2;
        const float cacc = (level == 0) ? ca0 : (level == 1) ? ca1 : ca2;
        if (s != START_STATE) {
            const int idx = state_start[s] + arc;
            if (idx < state_end[s]) {
                lab = ilabels[idx];
                sc  = cacc + arcs_weights[idx];
                fns = (float)to_states[idx];
                ok  = true;
            }
        }
    }

    if (ok && level == 2) who[lab] = (unsigned char)lane;
    __builtin_amdgcn_sched_barrier(0);
    if (ok && level == 1) who[lab] = (unsigned char)lane;
    __builtin_amdgcn_sched_barrier(0);
    if (ok && level == 0) who[lab] = (unsigned char)lane;
    __builtin_amdgcn_sched_barrier(0);

    float* __restrict__ so = out_scores + (size_t)b * VOCAB;
    float* __restrict__ no = out_next   + (size_t)b * VOCAB;
    const int sci = __float_as_int(sc);
    const int nsi = __float_as_int(fns);
    #pragma unroll
    for (int i = 0; i < NCHUNK; ++i) {
        const int v = (lane + i * WAVE) * 4;
        const unsigned w4 = *(const unsigned*)&who[v];
        const f32x4 dwv = *(const f32x4*)&arcs_weights[v];
        const i32x4 dnv = *(const i32x4*)&to_states[v];
        f32x4 rs, rx;
        #pragma unroll
        for (int j = 0; j < 4; ++j) {
            const unsigned wb = (w4 >> (8 * j)) & 0xFFu;
            const float scv = __int_as_float(
                __builtin_amdgcn_ds_bpermute((int)(wb << 2), sci));
            const float nsv = __int_as_float(
                __builtin_amdgcn_ds_bpermute((int)(wb << 2), nsi));
            const bool hit = (wb != 0xFFu);
            rs[j] = hit ? scv : accf + dwv[j];
            rx[j] = hit ? nsv : (float)dnv[j];
        }
        *(f32x4*)&so[v] = rs;
        *(f32x4*)&no[v] = rx;
    }
}

extern "C" void kernel_launch(void* const* d_in, const int* in_sizes, int n_in,
                              void* d_out, int out_size, void* d_ws, size_t ws_size,
                              hipStream_t stream) {
    const float* arcs_weights    = (const float*)d_in[0];
    const float* backoff_weights = (const float*)d_in[1];
    const int*   ilabels         = (const int*)d_in[2];
    const int*   to_states       = (const int*)d_in[3];
    const int*   backoff_to      = (const int*)d_in[4];
    const int*   state_start     = (const int*)d_in[5];
    const int*   state_end       = (const int*)d_in[6];
    const int*   states          = (const int*)d_in[7];

    const int B = in_sizes[7];                           // 8192 hypotheses
    float* out_scores = (float*)d_out;                   // first B*V floats
    float* out_next   = out_scores + (size_t)B * VOCAB;  // second B*V

    const int    grid   = (B + WAVES_PER_BLOCK - 1) / WAVES_PER_BLOCK;
    const size_t needed = (size_t)B * SLOTS * 4 * 3 + (size_t)B * 4;

    if (ws_size >= needed) {
        char* ws = (char*)d_ws;
        int*   ws_lab  = (int*)ws;
        float* ws_sc   = (float*)(ws + (size_t)B * SLOTS * 4);
        float* ws_ns   = (float*)(ws + (size_t)B * SLOTS * 8);
        float* ws_accf = (float*)(ws + (size_t)B * SLOTS * 12);

        build_overlay_kernel<<<grid, BLOCK, 0, stream>>>(
            arcs_weights, backoff_weights, ilabels, to_states, backoff_to,
            state_start, state_end, states,
            ws_lab, ws_sc, ws_ns, ws_accf, B);
        stream_merge_kernel<<<grid, BLOCK, 0, stream>>>(
            arcs_weights, to_states,
            ws_lab, ws_sc, ws_ns, ws_accf,
            out_scores, out_next, B);
    } else {
        ngram_fused_kernel<<<grid, BLOCK, 0, stream>>>(
            arcs_weights, backoff_weights, ilabels, to_states, backoff_to,
            state_start, state_end, states, out_scores, out_next, B);
    }
}